// Round 10
// baseline (2792.454 us; speedup 1.0000x reference)
//
#include <hip/hip_runtime.h>
#include <float.h>
#include <math.h>

// RQ-VAE residual quantizer.
// Screen: bf16-split MFMA distance GEMM (3-term hi/lo), top-2 per 128-code block.
// Select: numpy-f32 EMULATION on contested tokens (within RESCUE_EPS of winner):
//   d = fl((sr + sc) - 2*g), sr/sc = np pairwise sum (AVX512 leaf pattern),
//   g  = sequential k-ascending FMA chain (OpenBLAS sgemm microkernel order).
// Residual update emulates ref exactly: q_st = r + (q - r); r <- r - q_st.
// All emulation uses __fadd_rn/__fmul_rn/__fmaf_rn (no contraction).
// losses: commit == codebook numerically (eval) -> vq = 1.25 * sum_l mean(resid^2)
// resid (f32) lives in d_out's quantized region; quant_out finishes out = z - out.
// ws (floats): pval[N*64] | pidx[N*64] | cnorm[L*K] | counts[L*K] | lossP[L*8192]
//              | cbhiT[L*K*D bf16] | cbloT[L*K*D bf16]  == 33.8 MB total

#define NTOK 32768
#define DIM 256
#define KCODES 4096
#define NLAYER 4
#define NPART 64        // 2 candidates * 32 k-blocks
#define RESCUE_EPS 4e-3f
#define LOSSP_PER_LAYER (NTOK/4)

#define OFF_PVAL  0
#define OFF_PIDX  (NTOK*NPART)
#define OFF_CNORM (OFF_PIDX + NTOK*NPART)
#define OFF_COUNT (OFF_CNORM + NLAYER*KCODES)
#define OFF_LOSSP (OFF_COUNT + NLAYER*KCODES)
#define OFF_CBHI  (OFF_LOSSP + NLAYER*LOSSP_PER_LAYER)
#define OFF_CBLO  (OFF_CBHI + NLAYER*KCODES*DIM/2)   // bf16 array viewed as floats/2

typedef __attribute__((ext_vector_type(8))) short bf16x8;
typedef __attribute__((ext_vector_type(4))) float f32x4;

__device__ __forceinline__ unsigned short f2bf(float f) {          // RNE f32->bf16
    unsigned u = __float_as_uint(f);
    return (unsigned short)((u + 0x7FFFu + ((u >> 16) & 1u)) >> 16);
}
__device__ __forceinline__ float bf2f(unsigned short h) {
    return __uint_as_float(((unsigned)h) << 16);
}
__device__ __forceinline__ bool better(float v, int i, float bv, int bi) {
    return v < bv || (v == bv && i < bi);
}
__device__ __forceinline__ void top2_merge(float& v1, int& i1, float& v2, int& i2,
                                           float ov1, int oi1, float ov2, int oi2) {
    if (better(ov1, oi1, v1, i1)) {
        if (better(v1, i1, ov2, oi2)) { v2 = v1; i2 = i1; }
        else { v2 = ov2; i2 = oi2; }
        v1 = ov1; i1 = oi1;
    } else if (better(ov1, oi1, v2, i2)) { v2 = ov1; i2 = oi1; }
}
__device__ __forceinline__ void cv8(const float4 a, const float4 b, bf16x8& H, bf16x8& L) {
    float f[8] = {a.x, a.y, a.z, a.w, b.x, b.y, b.z, b.w};
#pragma unroll
    for (int q = 0; q < 8; ++q) {
        unsigned short h = f2bf(f[q]);
        H[q] = (short)h;
        L[q] = (short)f2bf(f[q] - bf2f(h));
    }
}

// ---- numpy f32 sum-of-squares emulation: pairwise, AVX512 SIMD leaf ----
// np pairwise: n=256 -> leaf(x[0:128]) + leaf(x[128:256]).
// leaf(128): 2 vector accs (16 lanes), chunks stride 32; then
// _mm512_reduce_add_ps halving tree (16->8->4->2->1).
__device__ float np_sumsq_leaf128(const float* __restrict__ x) {
    float r0[16], r1[16];
#pragma unroll
    for (int j = 0; j < 16; ++j) {
        r0[j] = __fmul_rn(x[j], x[j]);
        r1[j] = __fmul_rn(x[16 + j], x[16 + j]);
    }
#pragma unroll
    for (int i = 32; i < 128; i += 32) {
#pragma unroll
        for (int j = 0; j < 16; ++j) {
            r0[j] = __fadd_rn(r0[j], __fmul_rn(x[i + j], x[i + j]));
            r1[j] = __fadd_rn(r1[j], __fmul_rn(x[i + 16 + j], x[i + 16 + j]));
        }
    }
    float v[16];
#pragma unroll
    for (int j = 0; j < 16; ++j) v[j] = __fadd_rn(r0[j], r1[j]);
    float a[8];
#pragma unroll
    for (int j = 0; j < 8; ++j) a[j] = __fadd_rn(v[j], v[j + 8]);
    float b[4];
#pragma unroll
    for (int j = 0; j < 4; ++j) b[j] = __fadd_rn(a[j], a[j + 4]);
    float c0 = __fadd_rn(b[0], b[2]);
    float c1 = __fadd_rn(b[1], b[3]);
    return __fadd_rn(c0, c1);
}
__device__ float np_sumsq_256(const float* __restrict__ x) {
    return __fadd_rn(np_sumsq_leaf128(x), np_sumsq_leaf128(x + 128));
}

// one thread per code row: cnorm = np-emulated sum(c*c)
__global__ void cnorm_kernel(const float* __restrict__ cb, float* __restrict__ cnorm) {
    int idx = blockIdx.x * 256 + threadIdx.x;  // over L*K rows
    cnorm[idx] = np_sumsq_256(cb + (size_t)idx * DIM);
}

// Pre-split codebooks to bf16 hi/lo in k-step-tiled layout:
//   o = ((((layer*32+kb)*8+dtidx)*4+g)*128+n)*8+j  <->  cb[(layer*4096+kb*128+n)][dtidx*32+g*8+j]
__global__ void cb_split_kernel(const float* __restrict__ cb,
                                short* __restrict__ cbhiT, short* __restrict__ cbloT) {
    size_t o = ((size_t)blockIdx.x * 256 + threadIdx.x) * 8;
    int n = (int)((o >> 3) & 127);
    int g = (int)((o >> 10) & 3);
    int dtidx = (int)((o >> 12) & 7);
    int kb = (int)((o >> 15) & 31);
    int layer = (int)(o >> 20);
    const float* srcp = cb + ((size_t)(layer * KCODES + kb * 128 + n)) * DIM + dtidx * 32 + g * 8;
    float4 f0 = ((const float4*)srcp)[0];
    float4 f1 = ((const float4*)srcp)[1];
    bf16x8 H, L;
    cv8(f0, f1, H, L);
    *(bf16x8*)&cbhiT[o] = H;
    *(bf16x8*)&cbloT[o] = L;
}

// 128x128 tile, 4 waves (2x2), 16x16x32 bf16 MFMA, 3-term hi/lo split.
// grid = 256 mb * 32 kb = 8192 blocks. (screen only - approximate scores)
__launch_bounds__(256, 2)
__global__ void dist_mfma_kernel(const float* __restrict__ src,      // f32 rows [NTOK][DIM]
                                 const short* __restrict__ cbhiT,    // this layer, tiled
                                 const short* __restrict__ cbloT,
                                 const float* __restrict__ cnorm,    // this layer [KCODES]
                                 float* __restrict__ pval, int* __restrict__ pidx) {
    __shared__ __align__(16) short lsAhi[4096], lsAlo[4096], lsBhi[4096], lsBlo[4096];
    const int tid = threadIdx.x;
    const int kb = blockIdx.x & 31, mb = blockIdx.x >> 5;
    const int m0 = mb * 128, k0 = kb * 128;
    const int lane = tid & 63, w = tid >> 6;
    const int wm = w >> 1, wn = w & 1;
    const int lg = lane >> 4, lr = lane & 15;
    const int arow = tid & 127, ahalf = tid >> 7;

    f32x4 acc[4][4];
#pragma unroll
    for (int i = 0; i < 4; ++i)
#pragma unroll
        for (int j = 0; j < 4; ++j) acc[i][j] = (f32x4){0.f, 0.f, 0.f, 0.f};

    for (int dtidx = 0; dtidx < 8; ++dtidx) {
        const float* ap = src + (size_t)(m0 + arow) * DIM + dtidx * 32 + ahalf * 16;
        float4 f0 = ((const float4*)ap)[0];
        float4 f1 = ((const float4*)ap)[1];
        float4 f2 = ((const float4*)ap)[2];
        float4 f3 = ((const float4*)ap)[3];
        bf16x8 H0, L0, H1, L1;
        cv8(f0, f1, H0, L0);
        cv8(f2, f3, H1, L1);
        const int g0 = ahalf * 2;
        *(bf16x8*)&lsAhi[((g0) * 128 + arow) * 8] = H0;
        *(bf16x8*)&lsAlo[((g0) * 128 + arow) * 8] = L0;
        *(bf16x8*)&lsAhi[((g0 + 1) * 128 + arow) * 8] = H1;
        *(bf16x8*)&lsAlo[((g0 + 1) * 128 + arow) * 8] = L1;
        const bf16x8* bh = (const bf16x8*)(cbhiT + ((size_t)(kb * 8 + dtidx)) * 4096);
        const bf16x8* bl = (const bf16x8*)(cbloT + ((size_t)(kb * 8 + dtidx)) * 4096);
        ((bf16x8*)lsBhi)[tid] = bh[tid];
        ((bf16x8*)lsBhi)[256 + tid] = bh[256 + tid];
        ((bf16x8*)lsBlo)[tid] = bl[tid];
        ((bf16x8*)lsBlo)[256 + tid] = bl[256 + tid];
        __syncthreads();
        bf16x8 aH[4], aL[4], bH[4], bL[4];
#pragma unroll
        for (int mt = 0; mt < 4; ++mt) {
            int off = (lg * 128 + wm * 64 + mt * 16 + lr) * 8;
            aH[mt] = *(const bf16x8*)&lsAhi[off];
            aL[mt] = *(const bf16x8*)&lsAlo[off];
        }
#pragma unroll
        for (int nt = 0; nt < 4; ++nt) {
            int off = (lg * 128 + wn * 64 + nt * 16 + lr) * 8;
            bH[nt] = *(const bf16x8*)&lsBhi[off];
            bL[nt] = *(const bf16x8*)&lsBlo[off];
        }
#pragma unroll
        for (int mt = 0; mt < 4; ++mt)
#pragma unroll
            for (int nt = 0; nt < 4; ++nt) {
                acc[mt][nt] = __builtin_amdgcn_mfma_f32_16x16x32_bf16(aH[mt], bH[nt], acc[mt][nt], 0, 0, 0);
                acc[mt][nt] = __builtin_amdgcn_mfma_f32_16x16x32_bf16(aH[mt], bL[nt], acc[mt][nt], 0, 0, 0);
                acc[mt][nt] = __builtin_amdgcn_mfma_f32_16x16x32_bf16(aL[mt], bH[nt], acc[mt][nt], 0, 0, 0);
            }
        __syncthreads();
    }

    float cn[4];
#pragma unroll
    for (int nt = 0; nt < 4; ++nt) cn[nt] = cnorm[k0 + wn * 64 + nt * 16 + lr];
    float* mb_buf = (float*)lsAhi;  // safe: all waves passed the final barrier
#pragma unroll
    for (int mt = 0; mt < 4; ++mt)
#pragma unroll
        for (int r = 0; r < 4; ++r) {
            float v1 = FLT_MAX, v2 = FLT_MAX;
            int i1 = 0x7FFFFFFF, i2 = 0x7FFFFFFF;
#pragma unroll
            for (int nt = 0; nt < 4; ++nt) {
                float s = fmaf(-2.f, acc[mt][nt][r], cn[nt]);
                int kx = k0 + wn * 64 + nt * 16 + lr;
                if (better(s, kx, v1, i1)) { v2 = v1; i2 = i1; v1 = s; i1 = kx; }
                else if (better(s, kx, v2, i2)) { v2 = s; i2 = kx; }
            }
#pragma unroll
            for (int off = 1; off < 16; off <<= 1) {
                float ov1 = __shfl_xor(v1, off);
                int oi1 = __shfl_xor(i1, off);
                float ov2 = __shfl_xor(v2, off);
                int oi2 = __shfl_xor(i2, off);
                top2_merge(v1, i1, v2, i2, ov1, oi1, ov2, oi2);
            }
            if (lr == 0) {
                int row = mt * 16 + lg * 4 + r;
                float* p = mb_buf + (wn * 128 + wm * 64 + row) * 4;
                p[0] = v1; p[1] = __int_as_float(i1);
                p[2] = v2; p[3] = __int_as_float(i2);
            }
        }
    __syncthreads();
    if (wn == 0) {
        int row = lane;
        const float* p0 = mb_buf + (wm * 64 + row) * 4;
        const float* p1 = mb_buf + (128 + wm * 64 + row) * 4;
        float v1 = p0[0], v2 = p0[2];
        int i1 = __float_as_int(p0[1]), i2 = __float_as_int(p0[3]);
        top2_merge(v1, i1, v2, i2, p1[0], __float_as_int(p1[1]), p1[2], __float_as_int(p1[3]));
        size_t base = (size_t)(m0 + wm * 64 + row) * NPART + kb * 2;
        pval[base] = v1; pidx[base] = i1;
        pval[base + 1] = v2; pidx[base + 1] = i2;
    }
}

// one wave per token: MFMA-score argmin over 64 partials; on near-ties,
// np-f32-emulated d for all candidates decides (matches numpy reference bits).
// Then emulated residual update r <- r - (r + (q - r)); histogram; loss partial.
__global__ void finalize_kernel(const float* __restrict__ pval, const int* __restrict__ pidx,
                                const float* __restrict__ cb_layer,
                                const float* __restrict__ cnormnp,
                                const float* __restrict__ src, float* __restrict__ resid,
                                float* __restrict__ counts, float* __restrict__ outIdx,
                                float* __restrict__ lossPart) {
    __shared__ float wsum[4];
    const int tid = threadIdx.x;
    const int wave = tid >> 6, lane = tid & 63;
    const int n = blockIdx.x * 4 + wave;

    const float pv = pval[(size_t)n * NPART + lane];
    const int pi = pidx[(size_t)n * NPART + lane];

    float bv = pv;
    int bi = pi;
#pragma unroll
    for (int off = 32; off > 0; off >>= 1) {
        float ov = __shfl_xor(bv, off);
        int oi = __shfl_xor(bi, off);
        if (ov < bv || (ov == bv && oi < bi)) { bv = ov; bi = oi; }
    }

    const float4* r4 = (const float4*)(src + (size_t)n * DIM);
    float4 r = r4[lane];

    unsigned long long cmask = __ballot(pv <= bv + RESCUE_EPS);
    if (__popcll(cmask) > 1) {
        const float* rrow = src + (size_t)n * DIM;
        float sr = 0.f;
        if (lane == 0) sr = np_sumsq_256(rrow);   // np pairwise sum(r*r)
        sr = __shfl(sr, 0);
        float dmy = FLT_MAX;
        int imy = 0x7FFFFFFF;
        if (pv <= bv + RESCUE_EPS) {
            const float* crow = cb_layer + (size_t)pi * DIM;
            float acc = 0.f;                       // OpenBLAS sgemm k-chain
            for (int k = 0; k < DIM; ++k) acc = __fmaf_rn(rrow[k], crow[k], acc);
            dmy = __fsub_rn(__fadd_rn(sr, cnormnp[pi]), __fmul_rn(2.f, acc));
            imy = pi;
        }
#pragma unroll
        for (int off = 32; off > 0; off >>= 1) {
            float od = __shfl_xor(dmy, off);
            int oi = __shfl_xor(imy, off);
            if (od < dmy || (od == dmy && oi < imy)) { dmy = od; imy = oi; }
        }
        bi = imy;
    }

    if (lane == 0) {
        outIdx[n] = (float)bi;
        atomicAdd(&counts[bi], 1.0f);
    }
    // emulated straight-through update: q_st = r + (q - r); nr = r - q_st
    const float4 q = ((const float4*)(cb_layer + (size_t)bi * DIM))[lane];
    float4 nr;
    {
        float qst;
        qst = __fadd_rn(r.x, __fsub_rn(q.x, r.x)); nr.x = __fsub_rn(r.x, qst);
        qst = __fadd_rn(r.y, __fsub_rn(q.y, r.y)); nr.y = __fsub_rn(r.y, qst);
        qst = __fadd_rn(r.z, __fsub_rn(q.z, r.z)); nr.z = __fsub_rn(r.z, qst);
        qst = __fadd_rn(r.w, __fsub_rn(q.w, r.w)); nr.w = __fsub_rn(r.w, qst);
    }
    ((float4*)(resid + (size_t)n * DIM))[lane] = nr;
    float s = nr.x * nr.x + nr.y * nr.y + nr.z * nr.z + nr.w * nr.w;
#pragma unroll
    for (int off = 32; off > 0; off >>= 1) s += __shfl_xor(s, off);
    if (lane == 0) wsum[wave] = s;
    __syncthreads();
    if (tid == 0) lossPart[blockIdx.x] = wsum[0] + wsum[1] + wsum[2] + wsum[3];
}

// in-place: out (holding final residual) -> z - out
__global__ void quant_out_kernel(const float* __restrict__ z, float* __restrict__ out) {
    const float4* z4 = (const float4*)z;
    float4* o4 = (float4*)out;
    size_t stride = (size_t)gridDim.x * blockDim.x;
    for (size_t i = (size_t)blockIdx.x * blockDim.x + threadIdx.x; i < (size_t)NTOK * DIM / 4; i += stride) {
        float4 a = z4[i], b = o4[i];
        o4[i] = make_float4(a.x - b.x, a.y - b.y, a.z - b.z, a.w - b.w);
    }
}

__global__ void scalars_kernel(const float* __restrict__ lossPart, const float* __restrict__ counts,
                               float* __restrict__ out) {
    __shared__ float red[256];
    __shared__ float perpAcc;
    int tid = threadIdx.x;
    float s = 0.f;
    for (int i = tid; i < NLAYER * LOSSP_PER_LAYER; i += 256) s += lossPart[i];
    red[tid] = s;
    __syncthreads();
    for (int w = 128; w > 0; w >>= 1) {
        if (tid < w) red[tid] += red[tid + w];
        __syncthreads();
    }
    if (tid == 0) {
        out[0] = 1.25f * red[0] / (float)((size_t)NTOK * DIM);
        perpAcc = 0.f;
    }
    __syncthreads();
    for (int l = 0; l < NLAYER; ++l) {
        float e = 0.f;
        for (int k = tid; k < KCODES; k += 256) {
            float p = counts[l * KCODES + k] * (1.0f / NTOK);
            e += p * logf(p + 1e-10f);
        }
        red[tid] = e;
        __syncthreads();
        for (int w = 128; w > 0; w >>= 1) {
            if (tid < w) red[tid] += red[tid + w];
            __syncthreads();
        }
        if (tid == 0) perpAcc += expf(-red[0]);
        __syncthreads();
    }
    if (tid == 0) out[1] = perpAcc;
}

extern "C" void kernel_launch(void* const* d_in, const int* in_sizes, int n_in,
                              void* d_out, int out_size, void* d_ws, size_t ws_size,
                              hipStream_t stream) {
    const float* z = (const float*)d_in[0];
    const float* cb = (const float*)d_in[1];
    float* out = (float*)d_out;
    float* ws = (float*)d_ws;

    float* pval = ws + OFF_PVAL;
    int* pidx = (int*)(ws + OFF_PIDX);
    float* cnorm = ws + OFF_CNORM;
    float* counts = ws + OFF_COUNT;
    float* lossP = ws + OFF_LOSSP;
    short* cbhiT = (short*)(ws + OFF_CBHI);
    short* cbloT = (short*)(ws + OFF_CBLO);

    float* resid = out;                    // quantized region doubles as resid scratch
    float* idxOut = out + (size_t)NTOK * DIM;

    hipMemsetAsync(counts, 0, (size_t)(NLAYER * KCODES + NLAYER * LOSSP_PER_LAYER) * sizeof(float),
                   stream);
    cnorm_kernel<<<NLAYER * KCODES / 256, 256, 0, stream>>>(cb, cnorm);
    cb_split_kernel<<<NLAYER * KCODES * DIM / 8 / 256, 256, 0, stream>>>(cb, cbhiT, cbloT);

    const float* src = z;
    for (int l = 0; l < NLAYER; ++l) {
        dist_mfma_kernel<<<(NTOK / 128) * (KCODES / 128), 256, 0, stream>>>(
            src, cbhiT + (size_t)l * KCODES * DIM, cbloT + (size_t)l * KCODES * DIM,
            cnorm + l * KCODES, pval, pidx);
        finalize_kernel<<<NTOK / 4, 256, 0, stream>>>(
            pval, pidx, cb + (size_t)l * KCODES * DIM, cnorm + l * KCODES, src, resid,
            counts + l * KCODES, idxOut + (size_t)l * NTOK, lossP + l * LOSSP_PER_LAYER);
        src = resid;
    }
    quant_out_kernel<<<2048, 256, 0, stream>>>(z, out);
    scalars_kernel<<<1, 256, 0, stream>>>(lossP, counts, out + (size_t)NTOK * DIM + NLAYER * NTOK);
}